// Round 15
// baseline (252.778 us; speedup 1.0000x reference)
//
#include <hip/hip_runtime.h>

typedef unsigned short ushort_t;
typedef __attribute__((ext_vector_type(8))) unsigned short ushort8;
typedef __attribute__((ext_vector_type(4))) unsigned short ushort4v;
typedef __attribute__((ext_vector_type(8))) __bf16 bf16x8;
typedef __attribute__((ext_vector_type(4))) float f32x4;
typedef __attribute__((ext_vector_type(4))) float f4;
typedef __attribute__((ext_vector_type(4))) unsigned int uint4v;

#define B_ 32
#define C_ 1024
#define N_ 512
#define O_ 256

__device__ inline float bf2f(unsigned short u) {
  unsigned int i = ((unsigned int)u) << 16;
  return __builtin_bit_cast(float, i);
}
__device__ inline unsigned short f2bf(float f) {
  unsigned int i = __builtin_bit_cast(unsigned int, f);
  i += 0x7FFFu + ((i >> 16) & 1u);   // round-to-nearest-even
  return (unsigned short)(i >> 16);
}

// packed bf16x2 dot product: acc += a.lo*b.lo + a.hi*b.hi  (full-rate VOP3P)
#define DOT2(acc_, a_, b_)                                                  \
  asm("v_dot2_f32_bf16 %0, %1, %2, %0" : "+v"(acc_) : "v"(a_), "v"(b_))
// pack two fp32 -> bf16x2 (lo = s0, hi = s1), RNE
#define CVTPK(dst_, lo_, hi_)                                               \
  asm("v_cvt_pk_bf16_f32 %0, %1, %2" : "=v"(dst_) : "v"(lo_), "v"(hi_))

// async global->LDS, 16B per lane; LDS dest = wave-uniform base + lane*16
__device__ inline void gl_lds16(const ushort_t* g, ushort_t* l) {
  __builtin_amdgcn_global_load_lds(
      (const __attribute__((address_space(1))) void*)g,
      (__attribute__((address_space(3))) void*)l, 16, 0, 0);
}

// upper-triangle tile enumeration (nt <= mt), 10 tiles of a 4x4 grid
__device__ __constant__ const int TRI_NT[10] = {0, 0, 0, 0, 1, 1, 1, 2, 2, 3};
__device__ __constant__ const int TRI_MT[10] = {0, 1, 2, 3, 1, 2, 3, 2, 3, 3};

// ---------------- Phase 0: xo [b][c][n] fp32 -> xoT [b][n][c] bf16 ----------
__global__ __launch_bounds__(256) void k_transpose(const float* __restrict__ xo,
                                                   ushort_t* __restrict__ xoT) {
  __shared__ float tile[64][65];
  const int tn = blockIdx.x, tc = blockIdx.y, b = blockIdx.z;
  const int c0 = tc * 64, n0 = tn * 64;
  const int t = threadIdx.x;
  const int tr = t >> 4, tq = t & 15;
  const float* src = xo + ((size_t)b * C_ + c0) * N_ + n0;
#pragma unroll
  for (int p = 0; p < 4; ++p) {
    int c = p * 16 + tr;
    f4 v = *(const f4*)(src + (size_t)c * N_ + tq * 4);
    tile[c][tq * 4 + 0] = v[0];
    tile[c][tq * 4 + 1] = v[1];
    tile[c][tq * 4 + 2] = v[2];
    tile[c][tq * 4 + 3] = v[3];
  }
  __syncthreads();
  ushort_t* dst = xoT + ((size_t)b * N_ + n0) * C_ + c0;
#pragma unroll
  for (int p = 0; p < 4; ++p) {
    int n = p * 16 + tr;
    ushort4v u;
#pragma unroll
    for (int j = 0; j < 4; ++j) u[j] = f2bf(tile[tq * 4 + j][n]);
    *(ushort4v*)(dst + (size_t)n * C_ + tq * 4) = u;
  }
}

// ------- shared 128x128 bf16 MFMA GEMM mainloop, 2-phase double-buffer ------
// C[r][c] = sum_k A[r][k] * B[c][k]  (both row-major, K contiguous)
// LDS bank-swizzled: 16B chunk c of row r at chunk c ^ ((r>>1)&3).
template <int KSTEPS, int LDK>
__device__ inline void gemm_main(const ushort_t* __restrict__ Arows,
                                 const ushort_t* __restrict__ Brows,
                                 ushort_t* lds, f32x4 (&acc)[4][4], int t) {
  ushort_t* lds_a = lds;
  ushort_t* lds_b = lds + 8192;
  const int lane = t & 63, w = t >> 6;
  const int wr = w >> 1, wc = w & 1;
  const int l16 = lane & 15, lg = lane >> 4;
  const int srow = w * 32 + (lane >> 2);     // + j*16
  const int skp = (((lane & 3) ^ ((lane >> 3) & 3)) * 8);  // swizzled src chunk
  const int lgsw = ((lg ^ ((l16 >> 1) & 3))) * 8;          // swizzled read chunk
#define STAGE(s_, buf_)                                                     \
  {                                                                         \
    _Pragma("unroll") for (int j = 0; j < 2; ++j) {                         \
      const int row = srow + j * 16;                                        \
      gl_lds16(Arows + (size_t)row * LDK + (s_)*32 + skp,                   \
               lds_a + (buf_)*4096 + (w * 2 + j) * 512);                    \
      gl_lds16(Brows + (size_t)row * LDK + (s_)*32 + skp,                   \
               lds_b + (buf_)*4096 + (w * 2 + j) * 512);                    \
    }                                                                       \
  }
  STAGE(0, 0)
  __syncthreads();
  int buf = 0;
  for (int s = 0; s < KSTEPS; ++s) {
    if (s + 1 < KSTEPS) STAGE(s + 1, buf ^ 1)
    ushort8 au[4], bu[4];
#pragma unroll
    for (int i = 0; i < 4; ++i) {
      au[i] = *(const ushort8*)&lds_a[buf * 4096 + (wr * 64 + i * 16 + l16) * 32 + lgsw];
      bu[i] = *(const ushort8*)&lds_b[buf * 4096 + (wc * 64 + i * 16 + l16) * 32 + lgsw];
    }
#pragma unroll
    for (int ai = 0; ai < 4; ++ai)
#pragma unroll
      for (int bi = 0; bi < 4; ++bi)
        acc[ai][bi] = __builtin_amdgcn_mfma_f32_16x16x32_bf16(
            __builtin_bit_cast(bf16x8, au[ai]), __builtin_bit_cast(bf16x8, bu[bi]),
            acc[ai][bi], 0, 0, 0);
    __syncthreads();   // drains vmcnt(0)+lgkmcnt(0): next-buf stage complete
    buf ^= 1;
  }
#undef STAGE
}

#define CT_LD 136  // C-tile LDS stride (elems)

// ---------------- Phase 1: S[b] = xoT[b]*xoT[b]^T, upper-triangle tiles -----
// grid (32 b, 10 tri-tiles); b fastest -> all tiles of batch b on XCD b%8.
// Mirror pass writes S[m][n] and produces col-sum sq partials.
__global__ __launch_bounds__(256, 3) void k_sgemm(const ushort_t* __restrict__ xoT,
                                                  ushort_t* __restrict__ S,
                                                  float* __restrict__ sqp) {
  __shared__ ushort_t lds[128 * CT_LD];  // gemm staging, then bf16 C-tile
  const int b = blockIdx.x, y = blockIdx.y;
  const int nt = TRI_NT[y], mt = TRI_MT[y];
  const int n0 = nt * 128, m0 = mt * 128;
  const ushort_t* Ab = xoT + (size_t)b * N_ * C_ + (size_t)n0 * C_;
  const ushort_t* Bb = xoT + (size_t)b * N_ * C_ + (size_t)m0 * C_;
  f32x4 acc[4][4] = {};
  const int t = threadIdx.x;
  gemm_main<C_ / 32, C_>(Ab, Bb, lds, acc, t);
  const int lane = t & 63, w = t >> 6, wr = w >> 1, wc = w & 1;
  const int l16 = lane & 15, lg = lane >> 4;
#pragma unroll
  for (int ai = 0; ai < 4; ++ai)
#pragma unroll
    for (int bi = 0; bi < 4; ++bi)
#pragma unroll
      for (int j = 0; j < 4; ++j) {
        int r = wr * 64 + ai * 16 + lg * 4 + j;
        int c = wc * 64 + bi * 16 + l16;
        lds[r * CT_LD + c] = f2bf(acc[ai][bi][j]);
      }
  __syncthreads();
  ushort_t* Sb = S + (size_t)b * N_ * N_;
  // normal pass: coalesced store of (n0,m0) tile + row-sum sq -> sqp[mt][n0+r]
  {
    float* sqpb = sqp + ((size_t)mt * B_ + b) * N_ + n0;
#pragma unroll
    for (int p = 0; p < 8; ++p) {
      int id = p * 256 + t;
      int r = id >> 4, cc = (id & 15) * 8;
      ushort8 v = *(const ushort8*)&lds[r * CT_LD + cc];
      *(ushort8*)(Sb + (size_t)(n0 + r) * N_ + m0 + cc) = v;
      float s8 = 0.f;
#pragma unroll
      for (int j = 0; j < 8; ++j) {
        float f = bf2f(v[j]);
        s8 += f * f;
      }
      s8 += __shfl_xor(s8, 1, 64);
      s8 += __shfl_xor(s8, 2, 64);
      s8 += __shfl_xor(s8, 4, 64);
      s8 += __shfl_xor(s8, 8, 64);
      if ((t & 15) == 0) sqpb[r] = s8;
    }
  }
  // mirror pass (off-diagonal): store (m0,n0) tile transposed + col-sum sq
  if (nt != mt) {
    float* sqpc = sqp + ((size_t)nt * B_ + b) * N_ + m0;
#pragma unroll
    for (int p = 0; p < 8; ++p) {
      int id = p * 256 + t;
      int rr = id >> 4, cc = (id & 15) * 8;   // rr: col of C = row of mirror
      ushort8 v;
#pragma unroll
      for (int j = 0; j < 8; ++j) v[j] = lds[(cc + j) * CT_LD + rr];
      *(ushort8*)(Sb + (size_t)(m0 + rr) * N_ + n0 + cc) = v;
      float s8 = 0.f;
#pragma unroll
      for (int j = 0; j < 8; ++j) {
        float f = bf2f(v[j]);
        s8 += f * f;
      }
      s8 += __shfl_xor(s8, 1, 64);
      s8 += __shfl_xor(s8, 2, 64);
      s8 += __shfl_xor(s8, 4, 64);
      s8 += __shfl_xor(s8, 8, 64);
      if ((t & 15) == 0) sqpc[rr] = s8;   // col-sum of col (m0+rr) over n-panel
    }
  }
}

// ---------------- Phase 2: D = sqrt(max(sq_n + sq_m - 2*S.S^T, eps)) --------
// Upper-triangle tiles + mirror store (D symmetric). grid (32 b, 10 tiles).
__global__ __launch_bounds__(256, 3) void k_dgemm(const ushort_t* __restrict__ S,
                                                  const float* __restrict__ sqp,
                                                  ushort_t* __restrict__ D) {
  __shared__ ushort_t lds[128 * CT_LD];  // gemm staging, then bf16 D-tile
  __shared__ float sqn[128], sqm[128];
  const int b = blockIdx.x, y = blockIdx.y;
  const int nt = TRI_NT[y], mt = TRI_MT[y];
  const int n0 = nt * 128, m0 = mt * 128;
  const int t = threadIdx.x;
  {
    const int idx = (t < 128) ? (n0 + t) : (m0 + (t - 128));
    float s = 0.f;
#pragma unroll
    for (int p = 0; p < 4; ++p) s += sqp[((size_t)p * B_ + b) * N_ + idx];
    if (t < 128)
      sqn[t] = s;
    else
      sqm[t - 128] = s;
  }
  const ushort_t* Ab = S + (size_t)b * N_ * N_ + (size_t)n0 * N_;
  const ushort_t* Bb = S + (size_t)b * N_ * N_ + (size_t)m0 * N_;
  f32x4 acc[4][4] = {};
  gemm_main<N_ / 32, N_>(Ab, Bb, lds, acc, t);
  const int lane = t & 63, w = t >> 6, wr = w >> 1, wc = w & 1;
  const int l16 = lane & 15, lg = lane >> 4;
#pragma unroll
  for (int ai = 0; ai < 4; ++ai)
#pragma unroll
    for (int bi = 0; bi < 4; ++bi)
#pragma unroll
      for (int j = 0; j < 4; ++j) {
        int nl = wr * 64 + ai * 16 + lg * 4 + j;
        int ml = wc * 64 + bi * 16 + l16;
        float d2 = sqn[nl] + sqm[ml] - 2.f * acc[ai][bi][j];
        lds[nl * CT_LD + ml] = f2bf(sqrtf(fmaxf(d2, 1e-12f)));
      }
  __syncthreads();
  ushort_t* Db = D + (size_t)b * N_ * N_;
#pragma unroll
  for (int p = 0; p < 8; ++p) {
    int id = p * 256 + t;
    int r = id >> 4, cc = (id & 15) * 8;
    *(ushort8*)(Db + (size_t)(n0 + r) * N_ + m0 + cc) = *(const ushort8*)&lds[r * CT_LD + cc];
  }
  if (nt != mt) {
#pragma unroll
    for (int p = 0; p < 8; ++p) {
      int id = p * 256 + t;
      int rr = id >> 4, cc = (id & 15) * 8;
      ushort8 v;
#pragma unroll
      for (int j = 0; j < 8; ++j) v[j] = lds[(cc + j) * CT_LD + rr];
      *(ushort8*)(Db + (size_t)(m0 + rr) * N_ + n0 + cc) = v;
    }
  }
}

// ---------------- Phase 3: partial[g][b][o] = sum_{k in 512-chunk} D*W ------
// No D staging: each wave reads its k-quarter of D via wave-uniform vector
// loads (1 line fetch + broadcast, L1-cached; 3 of 4 kb hit the same line).
// W raw-load/convert-late pipeline + v_dot2_f32_bf16 inner loop.
__global__ __launch_bounds__(256, 2) void k_dw(const ushort_t* __restrict__ Dm,
                                               const float* __restrict__ W,
                                               float* __restrict__ partial) {
  __shared__ float lds_f[4 * 8 * 256];  // cross-wave reduce buffer, 32 KiB
  const int g = blockIdx.x, t = threadIdx.x;
  const int k0 = g * 512;
  const int w = t >> 6, lane = t & 63;
  const int ks = w;                 // wave id: k-sub of 128 rows
  const int ob = lane * 4;          // 4 output cols
  float acc[32][4] = {};            // [batch][o] fp32, static indexing
  const float* Wb = W + ((size_t)(k0 + ks * 128)) * O_ + ob;
  const ushort_t* dquarter = Dm + k0 + ks * 128;  // + bb*(N*N) + kl
  f4 rA[8], rB[8];                  // raw W rows (fp32)
  unsigned int wp[4][4];            // packed bf16x2 [k-pair][o]
#define LOADRAW(dst, kb_)                                                    \
  {                                                                          \
    _Pragma("unroll") for (int r = 0; r < 8; ++r) dst[r] =                   \
        *(const f4*)(Wb + (size_t)((kb_)*8 + r) * O_);                       \
  }
#define CVT(raw_)                                                            \
  {                                                                          \
    _Pragma("unroll") for (int r = 0; r < 4; ++r) {                          \
      CVTPK(wp[r][0], raw_[2 * r][0], raw_[2 * r + 1][0]);                   \
      CVTPK(wp[r][1], raw_[2 * r][1], raw_[2 * r + 1][1]);                   \
      CVTPK(wp[r][2], raw_[2 * r][2], raw_[2 * r + 1][2]);                   \
      CVTPK(wp[r][3], raw_[2 * r][3], raw_[2 * r + 1][3]);                   \
    }                                                                        \
  }
#define COMP(kb_)                                                            \
  {                                                                          \
    const int kl = (kb_)*8;                                                  \
    _Pragma("unroll") for (int bb = 0; bb < 32; ++bb) {                      \
      uint4v dv4 = *(const uint4v*)(dquarter + (size_t)bb * (N_ * N_) + kl); \
      _Pragma("unroll") for (int j = 0; j < 4; ++j) {                        \
        DOT2(acc[bb][0], dv4[j], wp[j][0]);                                  \
        DOT2(acc[bb][1], dv4[j], wp[j][1]);                                  \
        DOT2(acc[bb][2], dv4[j], wp[j][2]);                                  \
        DOT2(acc[bb][3], dv4[j], wp[j][3]);                                  \
      }                                                                      \
    }                                                                        \
  }
  LOADRAW(rA, 0)
#pragma unroll 1
  for (int kb = 0; kb < 16; kb += 2) {
    LOADRAW(rB, kb + 1)   // issue next-phase loads first (stay outstanding)
    CVT(rA)               // waits only on rA (issued one full phase ago)
    COMP(kb)
    if (kb + 2 < 16) LOADRAW(rA, kb + 2)
    CVT(rB)
    COMP(kb + 1)
  }
#undef LOADRAW
#undef CVT
#undef COMP
  // ---- cross-wave reduction: acc over 4 waves -> partial[g][b][o] ----
#pragma unroll
  for (int c = 0; c < 4; ++c) {          // batch chunk: b = c*8 + q
#pragma unroll
    for (int q = 0; q < 8; ++q) {
      f4 v;
      v[0] = acc[c * 8 + q][0];
      v[1] = acc[c * 8 + q][1];
      v[2] = acc[c * 8 + q][2];
      v[3] = acc[c * 8 + q][3];
      *(f4*)&lds_f[(ks * 8 + q) * 256 + lane * 4] = v;
    }
    __syncthreads();
    {
      const int q2 = t >> 5, o = (t & 31) * 8;
      f4 s0 = {}, s1 = {};
#pragma unroll
      for (int k2 = 0; k2 < 4; ++k2) {
        f4 a0 = *(const f4*)&lds_f[(k2 * 8 + q2) * 256 + o];
        f4 a1 = *(const f4*)&lds_f[(k2 * 8 + q2) * 256 + o + 4];
        s0 += a0;
        s1 += a1;
      }
      float* P = partial + ((size_t)g * B_ + c * 8 + q2) * O_ + o;
      *(f4*)P = s0;
      *(f4*)(P + 4) = s1;
    }
    __syncthreads();
  }
}

// ---------------- Phase 4a: reduce 512 partials -> 8 -----------------------
__global__ __launch_bounds__(256) void k_red1(const float* __restrict__ partial,
                                              float* __restrict__ p2) {
  const int pg = blockIdx.x, b = blockIdx.y, t = threadIdx.x;
  float s = 0.f;
#pragma unroll 8
  for (int p = pg * 64; p < pg * 64 + 64; ++p)
    s += partial[((size_t)p * B_ + b) * O_ + t];
  p2[((size_t)pg * B_ + b) * O_ + t] = s;
}

// ---------------- Phase 4b: final sum + bias + L2 normalize ----------------
__global__ __launch_bounds__(256) void k_red2(const float* __restrict__ p2,
                                              const float* __restrict__ bias,
                                              float* __restrict__ out) {
  const int b = blockIdx.x, t = threadIdx.x;
  float s = 0.f;
#pragma unroll
  for (int pg = 0; pg < 8; ++pg) s += p2[((size_t)pg * B_ + b) * O_ + t];
  s += bias[t];
  float q = s * s;
#pragma unroll
  for (int off = 32; off; off >>= 1) q += __shfl_down(q, off, 64);
  __shared__ float lds[4];
  if ((t & 63) == 0) lds[t >> 6] = q;
  __syncthreads();
  float tot = lds[0] + lds[1] + lds[2] + lds[3];
  out[b * O_ + t] = s / fmaxf(sqrtf(tot), 1e-12f);
}

extern "C" void kernel_launch(void* const* d_in, const int* in_sizes, int n_in,
                              void* d_out, int out_size, void* d_ws, size_t ws_size,
                              hipStream_t stream) {
  const float* xo = (const float*)d_in[2];
  const float* W = (const float*)d_in[3];
  const float* bias = (const float*)d_in[4];
  float* out = (float*)d_out;

  char* ws = (char*)d_ws;
  // layout (bytes):
  //   [0, 32M)    xoT bf16  (reused as partial[512][32][256] fp32 = 16M in phase 3+)
  //   [32M, 48M)  S bf16
  //   [48M, 64M)  D bf16
  //   [64M, ..)   sqp fp32 [4][32][512] (256 KiB), p2 fp32 (256 KiB)
  const size_t OFF_S = 33554432, OFF_D = 50331648, OFF_SQP = 67108864,
               OFF_P2 = 67371008, NEED = 67633152;
  if (ws_size < NEED) return;  // insufficient workspace -> fail loudly
  ushort_t* xoT = (ushort_t*)ws;
  ushort_t* S = (ushort_t*)(ws + OFF_S);
  ushort_t* D = (ushort_t*)(ws + OFF_D);
  float* sqp = (float*)(ws + OFF_SQP);
  float* p2 = (float*)(ws + OFF_P2);
  float* partial = (float*)ws;  // aliases xoT (dead by phase 3)

  hipLaunchKernelGGL(k_transpose, dim3(8, 16, 32), dim3(256), 0, stream, xo, xoT);
  // b fastest -> XCD = b%8: per-batch panel reuse stays within one XCD's L2
  hipLaunchKernelGGL(k_sgemm, dim3(32, 10), dim3(256), 0, stream, xoT, S, sqp);
  hipLaunchKernelGGL(k_dgemm, dim3(32, 10), dim3(256), 0, stream, S, sqp, D);
  hipLaunchKernelGGL(k_dw, dim3(512), dim3(256), 0, stream, D, W, partial);
  hipLaunchKernelGGL(k_red1, dim3(8, 32), dim3(256), 0, stream, partial, p2);
  hipLaunchKernelGGL(k_red2, dim3(32), dim3(256), 0, stream, p2, bias, out);
}

// Round 16
// 140.035 us; speedup vs baseline: 1.8051x; 1.8051x over previous
//
#include <hip/hip_runtime.h>

typedef unsigned short ushort_t;
typedef __attribute__((ext_vector_type(8))) unsigned short ushort8;
typedef __attribute__((ext_vector_type(4))) unsigned short ushort4v;
typedef __attribute__((ext_vector_type(8))) __bf16 bf16x8;
typedef __attribute__((ext_vector_type(4))) float f32x4;
typedef __attribute__((ext_vector_type(4))) float f4;
typedef __attribute__((ext_vector_type(4))) unsigned int uint4v;

#define B_ 32
#define C_ 1024
#define N_ 512
#define O_ 256

__device__ inline float bf2f(unsigned short u) {
  unsigned int i = ((unsigned int)u) << 16;
  return __builtin_bit_cast(float, i);
}
__device__ inline unsigned short f2bf(float f) {
  unsigned int i = __builtin_bit_cast(unsigned int, f);
  i += 0x7FFFu + ((i >> 16) & 1u);   // round-to-nearest-even
  return (unsigned short)(i >> 16);
}

// packed bf16x2 dot product: acc += a.lo*b.lo + a.hi*b.hi  (full-rate VOP3P)
#define DOT2(acc_, a_, b_)                                                  \
  asm("v_dot2_f32_bf16 %0, %1, %2, %0" : "+v"(acc_) : "v"(a_), "v"(b_))
// pack two fp32 -> bf16x2 (lo = s0, hi = s1), RNE
#define CVTPK(dst_, lo_, hi_)                                               \
  asm("v_cvt_pk_bf16_f32 %0, %1, %2" : "=v"(dst_) : "v"(lo_), "v"(hi_))

// async global->LDS, 16B per lane; LDS dest = wave-uniform base + lane*16
__device__ inline void gl_lds16(const ushort_t* g, ushort_t* l) {
  __builtin_amdgcn_global_load_lds(
      (const __attribute__((address_space(1))) void*)g,
      (__attribute__((address_space(3))) void*)l, 16, 0, 0);
}

// upper-triangle tile enumeration (nt <= mt), 10 tiles of a 4x4 grid
__device__ __constant__ const int TRI_NT[10] = {0, 0, 0, 0, 1, 1, 1, 2, 2, 3};
__device__ __constant__ const int TRI_MT[10] = {0, 1, 2, 3, 1, 2, 3, 2, 3, 3};

// ---------------- Phase 0: xo [b][c][n] fp32 -> xoT [b][n][c] bf16 ----------
__global__ __launch_bounds__(256) void k_transpose(const float* __restrict__ xo,
                                                   ushort_t* __restrict__ xoT) {
  __shared__ float tile[64][65];
  const int tn = blockIdx.x, tc = blockIdx.y, b = blockIdx.z;
  const int c0 = tc * 64, n0 = tn * 64;
  const int t = threadIdx.x;
  const int tr = t >> 4, tq = t & 15;
  const float* src = xo + ((size_t)b * C_ + c0) * N_ + n0;
#pragma unroll
  for (int p = 0; p < 4; ++p) {
    int c = p * 16 + tr;
    f4 v = *(const f4*)(src + (size_t)c * N_ + tq * 4);
    tile[c][tq * 4 + 0] = v[0];
    tile[c][tq * 4 + 1] = v[1];
    tile[c][tq * 4 + 2] = v[2];
    tile[c][tq * 4 + 3] = v[3];
  }
  __syncthreads();
  ushort_t* dst = xoT + ((size_t)b * N_ + n0) * C_ + c0;
#pragma unroll
  for (int p = 0; p < 4; ++p) {
    int n = p * 16 + tr;
    ushort4v u;
#pragma unroll
    for (int j = 0; j < 4; ++j) u[j] = f2bf(tile[tq * 4 + j][n]);
    *(ushort4v*)(dst + (size_t)n * C_ + tq * 4) = u;
  }
}

// ------- shared 128x128 bf16 MFMA GEMM mainloop, 2-phase double-buffer ------
// C[r][c] = sum_k A[r][k] * B[c][k]  (both row-major, K contiguous)
// LDS bank-swizzled: 16B chunk c of row r at chunk c ^ ((r>>1)&3).
template <int KSTEPS, int LDK>
__device__ inline void gemm_main(const ushort_t* __restrict__ Arows,
                                 const ushort_t* __restrict__ Brows,
                                 ushort_t* lds, f32x4 (&acc)[4][4], int t) {
  ushort_t* lds_a = lds;
  ushort_t* lds_b = lds + 8192;
  const int lane = t & 63, w = t >> 6;
  const int wr = w >> 1, wc = w & 1;
  const int l16 = lane & 15, lg = lane >> 4;
  const int srow = w * 32 + (lane >> 2);     // + j*16
  const int skp = (((lane & 3) ^ ((lane >> 3) & 3)) * 8);  // swizzled src chunk
  const int lgsw = ((lg ^ ((l16 >> 1) & 3))) * 8;          // swizzled read chunk
#define STAGE(s_, buf_)                                                     \
  {                                                                         \
    _Pragma("unroll") for (int j = 0; j < 2; ++j) {                         \
      const int row = srow + j * 16;                                        \
      gl_lds16(Arows + (size_t)row * LDK + (s_)*32 + skp,                   \
               lds_a + (buf_)*4096 + (w * 2 + j) * 512);                    \
      gl_lds16(Brows + (size_t)row * LDK + (s_)*32 + skp,                   \
               lds_b + (buf_)*4096 + (w * 2 + j) * 512);                    \
    }                                                                       \
  }
  STAGE(0, 0)
  __syncthreads();
  int buf = 0;
  for (int s = 0; s < KSTEPS; ++s) {
    if (s + 1 < KSTEPS) STAGE(s + 1, buf ^ 1)
    ushort8 au[4], bu[4];
#pragma unroll
    for (int i = 0; i < 4; ++i) {
      au[i] = *(const ushort8*)&lds_a[buf * 4096 + (wr * 64 + i * 16 + l16) * 32 + lgsw];
      bu[i] = *(const ushort8*)&lds_b[buf * 4096 + (wc * 64 + i * 16 + l16) * 32 + lgsw];
    }
#pragma unroll
    for (int ai = 0; ai < 4; ++ai)
#pragma unroll
      for (int bi = 0; bi < 4; ++bi)
        acc[ai][bi] = __builtin_amdgcn_mfma_f32_16x16x32_bf16(
            __builtin_bit_cast(bf16x8, au[ai]), __builtin_bit_cast(bf16x8, bu[bi]),
            acc[ai][bi], 0, 0, 0);
    __syncthreads();   // drains vmcnt(0)+lgkmcnt(0): next-buf stage complete
    buf ^= 1;
  }
#undef STAGE
}

#define CT_LD 136  // C-tile LDS stride (elems)

// ---------------- Phase 1: S[b] = xoT[b]*xoT[b]^T, upper-triangle tiles -----
// grid (32 b, 10 tri-tiles); b fastest -> all tiles of batch b on XCD b%8.
// Mirror pass writes S[m][n] and produces col-sum sq partials.
__global__ __launch_bounds__(256, 3) void k_sgemm(const ushort_t* __restrict__ xoT,
                                                  ushort_t* __restrict__ S,
                                                  float* __restrict__ sqp) {
  __shared__ ushort_t lds[128 * CT_LD];  // gemm staging, then bf16 C-tile
  const int b = blockIdx.x, y = blockIdx.y;
  const int nt = TRI_NT[y], mt = TRI_MT[y];
  const int n0 = nt * 128, m0 = mt * 128;
  const ushort_t* Ab = xoT + (size_t)b * N_ * C_ + (size_t)n0 * C_;
  const ushort_t* Bb = xoT + (size_t)b * N_ * C_ + (size_t)m0 * C_;
  f32x4 acc[4][4] = {};
  const int t = threadIdx.x;
  gemm_main<C_ / 32, C_>(Ab, Bb, lds, acc, t);
  const int lane = t & 63, w = t >> 6, wr = w >> 1, wc = w & 1;
  const int l16 = lane & 15, lg = lane >> 4;
#pragma unroll
  for (int ai = 0; ai < 4; ++ai)
#pragma unroll
    for (int bi = 0; bi < 4; ++bi)
#pragma unroll
      for (int j = 0; j < 4; ++j) {
        int r = wr * 64 + ai * 16 + lg * 4 + j;
        int c = wc * 64 + bi * 16 + l16;
        lds[r * CT_LD + c] = f2bf(acc[ai][bi][j]);
      }
  __syncthreads();
  ushort_t* Sb = S + (size_t)b * N_ * N_;
  // normal pass: coalesced store of (n0,m0) tile + row-sum sq -> sqp[mt][n0+r]
  {
    float* sqpb = sqp + ((size_t)mt * B_ + b) * N_ + n0;
#pragma unroll
    for (int p = 0; p < 8; ++p) {
      int id = p * 256 + t;
      int r = id >> 4, cc = (id & 15) * 8;
      ushort8 v = *(const ushort8*)&lds[r * CT_LD + cc];
      *(ushort8*)(Sb + (size_t)(n0 + r) * N_ + m0 + cc) = v;
      float s8 = 0.f;
#pragma unroll
      for (int j = 0; j < 8; ++j) {
        float f = bf2f(v[j]);
        s8 += f * f;
      }
      s8 += __shfl_xor(s8, 1, 64);
      s8 += __shfl_xor(s8, 2, 64);
      s8 += __shfl_xor(s8, 4, 64);
      s8 += __shfl_xor(s8, 8, 64);
      if ((t & 15) == 0) sqpb[r] = s8;
    }
  }
  // mirror pass (off-diagonal): store (m0,n0) tile transposed + col-sum sq
  if (nt != mt) {
    float* sqpc = sqp + ((size_t)nt * B_ + b) * N_ + m0;
#pragma unroll
    for (int p = 0; p < 8; ++p) {
      int id = p * 256 + t;
      int rr = id >> 4, cc = (id & 15) * 8;   // rr: col of C = row of mirror
      ushort8 v;
#pragma unroll
      for (int j = 0; j < 8; ++j) v[j] = lds[(cc + j) * CT_LD + rr];
      *(ushort8*)(Sb + (size_t)(m0 + rr) * N_ + n0 + cc) = v;
      float s8 = 0.f;
#pragma unroll
      for (int j = 0; j < 8; ++j) {
        float f = bf2f(v[j]);
        s8 += f * f;
      }
      s8 += __shfl_xor(s8, 1, 64);
      s8 += __shfl_xor(s8, 2, 64);
      s8 += __shfl_xor(s8, 4, 64);
      s8 += __shfl_xor(s8, 8, 64);
      if ((t & 15) == 0) sqpc[rr] = s8;   // col-sum of col (m0+rr) over n-panel
    }
  }
}

// ---------------- Phase 2: D = sqrt(max(sq_n + sq_m - 2*S.S^T, eps)) --------
// Upper-triangle tiles + mirror store (D symmetric). grid (32 b, 10 tiles).
__global__ __launch_bounds__(256, 3) void k_dgemm(const ushort_t* __restrict__ S,
                                                  const float* __restrict__ sqp,
                                                  ushort_t* __restrict__ D) {
  __shared__ ushort_t lds[128 * CT_LD];  // gemm staging, then bf16 D-tile
  __shared__ float sqn[128], sqm[128];
  const int b = blockIdx.x, y = blockIdx.y;
  const int nt = TRI_NT[y], mt = TRI_MT[y];
  const int n0 = nt * 128, m0 = mt * 128;
  const int t = threadIdx.x;
  {
    const int idx = (t < 128) ? (n0 + t) : (m0 + (t - 128));
    float s = 0.f;
#pragma unroll
    for (int p = 0; p < 4; ++p) s += sqp[((size_t)p * B_ + b) * N_ + idx];
    if (t < 128)
      sqn[t] = s;
    else
      sqm[t - 128] = s;
  }
  const ushort_t* Ab = S + (size_t)b * N_ * N_ + (size_t)n0 * N_;
  const ushort_t* Bb = S + (size_t)b * N_ * N_ + (size_t)m0 * N_;
  f32x4 acc[4][4] = {};
  gemm_main<N_ / 32, N_>(Ab, Bb, lds, acc, t);
  const int lane = t & 63, w = t >> 6, wr = w >> 1, wc = w & 1;
  const int l16 = lane & 15, lg = lane >> 4;
#pragma unroll
  for (int ai = 0; ai < 4; ++ai)
#pragma unroll
    for (int bi = 0; bi < 4; ++bi)
#pragma unroll
      for (int j = 0; j < 4; ++j) {
        int nl = wr * 64 + ai * 16 + lg * 4 + j;
        int ml = wc * 64 + bi * 16 + l16;
        float d2 = sqn[nl] + sqm[ml] - 2.f * acc[ai][bi][j];
        lds[nl * CT_LD + ml] = f2bf(sqrtf(fmaxf(d2, 1e-12f)));
      }
  __syncthreads();
  ushort_t* Db = D + (size_t)b * N_ * N_;
#pragma unroll
  for (int p = 0; p < 8; ++p) {
    int id = p * 256 + t;
    int r = id >> 4, cc = (id & 15) * 8;
    *(ushort8*)(Db + (size_t)(n0 + r) * N_ + m0 + cc) = *(const ushort8*)&lds[r * CT_LD + cc];
  }
  if (nt != mt) {
#pragma unroll
    for (int p = 0; p < 8; ++p) {
      int id = p * 256 + t;
      int rr = id >> 4, cc = (id & 15) * 8;
      ushort8 v;
#pragma unroll
      for (int j = 0; j < 8; ++j) v[j] = lds[(cc + j) * CT_LD + rr];
      *(ushort8*)(Db + (size_t)(m0 + rr) * N_ + n0 + cc) = v;
    }
  }
}

// ---------------- Phase 3: partial[g][b][o] = sum_{k in 512-chunk} D*W ------
// LDS-staged D (latency decoupler) + W raw-load/convert-late pipeline +
// v_dot2_f32_bf16 inner loop. First W batch issued BEFORE the staging drain.
__global__ __launch_bounds__(256, 2) void k_dw(const ushort_t* __restrict__ Dm,
                                               const float* __restrict__ W,
                                               float* __restrict__ partial) {
  __shared__ ushort_t lds_d[32 * 512];  // [b][k] 32 KiB
  const int g = blockIdx.x, t = threadIdx.x;
  const int k0 = g * 512;
  const int w = t >> 6, lane = t & 63;
  const int ks = w;                 // wave id: k-sub of 128 rows
  const int ob = lane * 4;          // 4 output cols
  const float* Wb = W + ((size_t)(k0 + ks * 128)) * O_ + ob;
  f4 rA[8], rB[8];                  // raw W rows (fp32)
  unsigned int wp[4][4];            // packed bf16x2 [k-pair][o]
#define LOADRAW(dst, kb_)                                                    \
  {                                                                          \
    _Pragma("unroll") for (int r = 0; r < 8; ++r) dst[r] =                   \
        *(const f4*)(Wb + (size_t)((kb_)*8 + r) * O_);                       \
  }
  LOADRAW(rA, 0)   // W requests in flight before the staging drain
#pragma unroll
  for (int i = 0; i < 8; ++i) {
    int c = i * 256 + t;  // 0..2047 ; b = c>>6, kchunk = c&63
    gl_lds16(Dm + (size_t)(c >> 6) * (N_ * N_) + k0 + (c & 63) * 8,
             lds_d + (i * 256 + w * 64) * 8);
  }
  __syncthreads();
  float acc[32][4] = {};            // [batch][o] fp32, static indexing
  const ushort_t* dbase = &lds_d[ks * 128];
#define CVT(raw_)                                                            \
  {                                                                          \
    _Pragma("unroll") for (int r = 0; r < 4; ++r) {                          \
      CVTPK(wp[r][0], raw_[2 * r][0], raw_[2 * r + 1][0]);                   \
      CVTPK(wp[r][1], raw_[2 * r][1], raw_[2 * r + 1][1]);                   \
      CVTPK(wp[r][2], raw_[2 * r][2], raw_[2 * r + 1][2]);                   \
      CVTPK(wp[r][3], raw_[2 * r][3], raw_[2 * r + 1][3]);                   \
    }                                                                        \
  }
#define COMP(kb_)                                                            \
  {                                                                          \
    const int kl = (kb_)*8;                                                  \
    _Pragma("unroll") for (int bb = 0; bb < 32; ++bb) {                      \
      uint4v dv4 = *(const uint4v*)&dbase[bb * 512 + kl];                    \
      _Pragma("unroll") for (int j = 0; j < 4; ++j) {                        \
        DOT2(acc[bb][0], dv4[j], wp[j][0]);                                  \
        DOT2(acc[bb][1], dv4[j], wp[j][1]);                                  \
        DOT2(acc[bb][2], dv4[j], wp[j][2]);                                  \
        DOT2(acc[bb][3], dv4[j], wp[j][3]);                                  \
      }                                                                      \
    }                                                                        \
  }
#pragma unroll 1
  for (int kb = 0; kb < 16; kb += 2) {
    LOADRAW(rB, kb + 1)   // issue next-phase loads first (stay outstanding)
    CVT(rA)               // waits only on rA (issued one full phase ago)
    COMP(kb)
    if (kb + 2 < 16) LOADRAW(rA, kb + 2)
    CVT(rB)
    COMP(kb + 1)
  }
#undef LOADRAW
#undef CVT
#undef COMP
  // ---- cross-wave reduction: acc over 4 waves -> partial[g][b][o] ----
  __syncthreads();                       // compute done, lds_d dead
  float* lds_f = (float*)lds_d;          // [4 ks][8 bsub][256 o] = 32 KiB
#pragma unroll
  for (int c = 0; c < 4; ++c) {          // batch chunk: b = c*8 + q
#pragma unroll
    for (int q = 0; q < 8; ++q) {
      f4 v;
      v[0] = acc[c * 8 + q][0];
      v[1] = acc[c * 8 + q][1];
      v[2] = acc[c * 8 + q][2];
      v[3] = acc[c * 8 + q][3];
      *(f4*)&lds_f[(ks * 8 + q) * 256 + lane * 4] = v;
    }
    __syncthreads();
    {
      const int q2 = t >> 5, o = (t & 31) * 8;
      f4 s0 = {}, s1 = {};
#pragma unroll
      for (int k2 = 0; k2 < 4; ++k2) {
        f4 a0 = *(const f4*)&lds_f[(k2 * 8 + q2) * 256 + o];
        f4 a1 = *(const f4*)&lds_f[(k2 * 8 + q2) * 256 + o + 4];
        s0 += a0;
        s1 += a1;
      }
      float* P = partial + ((size_t)g * B_ + c * 8 + q2) * O_ + o;
      *(f4*)P = s0;
      *(f4*)(P + 4) = s1;
    }
    __syncthreads();
  }
}

// ---------------- Phase 4a: reduce 512 partials -> 8 -----------------------
__global__ __launch_bounds__(256) void k_red1(const float* __restrict__ partial,
                                              float* __restrict__ p2) {
  const int pg = blockIdx.x, b = blockIdx.y, t = threadIdx.x;
  float s = 0.f;
#pragma unroll 8
  for (int p = pg * 64; p < pg * 64 + 64; ++p)
    s += partial[((size_t)p * B_ + b) * O_ + t];
  p2[((size_t)pg * B_ + b) * O_ + t] = s;
}

// ---------------- Phase 4b: final sum + bias + L2 normalize ----------------
__global__ __launch_bounds__(256) void k_red2(const float* __restrict__ p2,
                                              const float* __restrict__ bias,
                                              float* __restrict__ out) {
  const int b = blockIdx.x, t = threadIdx.x;
  float s = 0.f;
#pragma unroll
  for (int pg = 0; pg < 8; ++pg) s += p2[((size_t)pg * B_ + b) * O_ + t];
  s += bias[t];
  float q = s * s;
#pragma unroll
  for (int off = 32; off; off >>= 1) q += __shfl_down(q, off, 64);
  __shared__ float lds[4];
  if ((t & 63) == 0) lds[t >> 6] = q;
  __syncthreads();
  float tot = lds[0] + lds[1] + lds[2] + lds[3];
  out[b * O_ + t] = s / fmaxf(sqrtf(tot), 1e-12f);
}

extern "C" void kernel_launch(void* const* d_in, const int* in_sizes, int n_in,
                              void* d_out, int out_size, void* d_ws, size_t ws_size,
                              hipStream_t stream) {
  const float* xo = (const float*)d_in[2];
  const float* W = (const float*)d_in[3];
  const float* bias = (const float*)d_in[4];
  float* out = (float*)d_out;

  char* ws = (char*)d_ws;
  // layout (bytes):
  //   [0, 32M)    xoT bf16  (reused as partial[512][32][256] fp32 = 16M in phase 3+)
  //   [32M, 48M)  S bf16
  //   [48M, 64M)  D bf16
  //   [64M, ..)   sqp fp32 [4][32][512] (256 KiB), p2 fp32 (256 KiB)
  const size_t OFF_S = 33554432, OFF_D = 50331648, OFF_SQP = 67108864,
               OFF_P2 = 67371008, NEED = 67633152;
  if (ws_size < NEED) return;  // insufficient workspace -> fail loudly
  ushort_t* xoT = (ushort_t*)ws;
  ushort_t* S = (ushort_t*)(ws + OFF_S);
  ushort_t* D = (ushort_t*)(ws + OFF_D);
  float* sqp = (float*)(ws + OFF_SQP);
  float* p2 = (float*)(ws + OFF_P2);
  float* partial = (float*)ws;  // aliases xoT (dead by phase 3)

  hipLaunchKernelGGL(k_transpose, dim3(8, 16, 32), dim3(256), 0, stream, xo, xoT);
  // b fastest -> XCD = b%8: per-batch panel reuse stays within one XCD's L2
  hipLaunchKernelGGL(k_sgemm, dim3(32, 10), dim3(256), 0, stream, xoT, S, sqp);
  hipLaunchKernelGGL(k_dgemm, dim3(32, 10), dim3(256), 0, stream, S, sqp, D);
  hipLaunchKernelGGL(k_dw, dim3(512), dim3(256), 0, stream, D, W, partial);
  hipLaunchKernelGGL(k_red1, dim3(8, 32), dim3(256), 0, stream, partial, p2);
  hipLaunchKernelGGL(k_red2, dim3(32), dim3(256), 0, stream, p2, bias, out);
}